// Round 4
// baseline (588.885 us; speedup 1.0000x reference)
//
#include <hip/hip_runtime.h>

typedef unsigned short U16;
typedef unsigned int U32;
typedef __bf16 bf16;
typedef bf16 bf16x8 __attribute__((ext_vector_type(8)));
typedef U16  u16x8  __attribute__((ext_vector_type(8)));
typedef float f32x4 __attribute__((ext_vector_type(4)));

// Exact 3-limb bf16 chop split: a == a1 + a2 + a3 (fp32 24-bit significand
// = 3 x 8-bit bf16 limbs; bf16 exponent range == fp32 so limbs never subnormal).
__device__ __forceinline__ void split3(float a, U16& o1, U16& o2, U16& o3) {
    U32 ua = __float_as_uint(a);
    float a1 = __uint_as_float(ua & 0xFFFF0000u);
    float r1 = a - a1;
    U32 u2 = __float_as_uint(r1);
    float a2 = __uint_as_float(u2 & 0xFFFF0000u);
    float r2 = r1 - a2;                     // fits bf16 exactly (<=8 sig bits)
    o1 = (U16)(ua >> 16);
    o2 = (U16)(u2 >> 16);
    o3 = (U16)(__float_as_uint(r2) >> 16);
}

__device__ __forceinline__ void split3x8(const float v[8], bf16x8& A1, bf16x8& A2, bf16x8& A3) {
    u16x8 e1, e2, e3;
    #pragma unroll
    for (int j = 0; j < 8; ++j) { U16 a, b, c; split3(v[j], a, b, c); e1[j] = a; e2[j] = b; e3[j] = c; }
    A1 = __builtin_bit_cast(bf16x8, e1);
    A2 = __builtin_bit_cast(bf16x8, e2);
    A3 = __builtin_bit_cast(bf16x8, e3);
}

// B=64, C=32, H=W=128, PERC=112(pad->128), NHID=128, NCLS=10. fp32 in, fp32 OUT.
// block = 256 threads = 4 waves = 64 pixels (one b, one row, half width).
// Round-2 kernel verified numerically identical to the fp32 VALU port (round-3
// bisect: bit-identical absmax); only change this round: fp32 output stores.

__global__ __launch_bounds__(256, 2)
void cann_kernel(const float* __restrict__ xg,  const float* __restrict__ w1g,
                 const float* __restrict__ b1g, const float* __restrict__ w2g,
                 const float* __restrict__ b2g, const float* __restrict__ gg,
                 const float* __restrict__ bg,  float* __restrict__ outg)
{
    __shared__ __align__(16) unsigned char smem[33792 + 3 * 8704];   // 59904 B
    float* sPf   = (float*)smem;                       // [64][132] f32
    U16*   sW2L0 = (U16*)(smem + 33792);               // [32][136] bf16 limb1
    U16*   sW2L1 = (U16*)(smem + 33792 + 8704);        // limb2
    U16*   sW2L2 = (U16*)(smem + 33792 + 2 * 8704);    // limb3
    float* dxl   = (float*)(smem + 33792);             // [64][33] f32 (after B4a)

    const int tid  = threadIdx.x;
    const int bid  = blockIdx.x;
    const int jseg = bid & 1;
    const int irow = (bid >> 1) & 127;
    const int b    = bid >> 8;
    const int jbase = jseg << 6;

    const int lane = tid & 63;
    const int wv   = tid >> 6;
    const int quad = lane >> 4;
    const int col  = lane & 15;

    // ---------------- Phase A: stage perc (fp32) + w2 limbs into LDS ----------
    {
        // perc channels 0..31 = x  (2048 floats, 8 per thread, float4 loads)
        int c  = tid >> 3;
        int j8 = (tid & 7) << 3;
        const float* src = xg + (b * 32 + c) * 16384 + irow * 128 + jbase + j8;
        float4 v0 = *(const float4*)src;
        float4 v1 = *(const float4*)(src + 4);
        sPf[(j8 + 0) * 132 + c] = v0.x;  sPf[(j8 + 1) * 132 + c] = v0.y;
        sPf[(j8 + 2) * 132 + c] = v0.z;  sPf[(j8 + 3) * 132 + c] = v0.w;
        sPf[(j8 + 4) * 132 + c] = v1.x;  sPf[(j8 + 5) * 132 + c] = v1.y;
        sPf[(j8 + 6) * 132 + c] = v1.z;  sPf[(j8 + 7) * 132 + c] = v1.w;

        // perc channels 32..111 = 8 shifted taps x 10 class channels
        #pragma unroll
        for (int pass = 0; pass < 5; ++pass) {
            int j   = tid + pass * 256;           // 1280 jobs: 80 ch x 16 pixel-quads
            int ch  = j >> 4;                     // 0..79
            int p4  = (j & 15) << 2;
            int cls = ch >> 3, t = ch & 7;
            int di = (int)((0x22211000u >> (4 * t)) & 0xFu) - 1;
            int dj = (int)((0x21020210u >> (4 * t)) & 0xFu) - 1;
            int row = irow + di;
            bool rok = (unsigned)row < 128u;
            const float* base = xg + (b * 32 + cls) * 16384 + row * 128;
            int cb = jbase + p4 + dj;
            #pragma unroll
            for (int r = 0; r < 4; ++r) {
                int cc = cb + r;
                float v = (rok && (unsigned)cc < 128u) ? base[cc] : 0.0f;
                sPf[(p4 + r) * 132 + 32 + ch] = v;
            }
        }
        // perc zero-pad k=112..127
        #pragma unroll
        for (int q = 0; q < 4; ++q) {
            int idx = tid + q * 256;              // 1024 jobs
            int p = idx >> 4, cc = idx & 15;
            sPf[p * 132 + 112 + cc] = 0.0f;
        }
        // w2 -> 3 bf16 limbs in LDS (each thread: 16 consecutive floats of one row)
        int n  = tid >> 3;
        int k0 = (tid & 7) << 4;
        const float* ws = w2g + n * 128 + k0;
        U16 t1[16], t2[16], t3[16];
        #pragma unroll
        for (int e = 0; e < 16; ++e) split3(ws[e], t1[e], t2[e], t3[e]);
        #define PK(t, e) ((U32)t[e] | ((U32)t[(e)+1] << 16))
        {
            uint4 q0 = make_uint4(PK(t1,0), PK(t1,2), PK(t1,4), PK(t1,6));
            uint4 q1 = make_uint4(PK(t1,8), PK(t1,10), PK(t1,12), PK(t1,14));
            *(uint4*)(sW2L0 + n * 136 + k0) = q0; *(uint4*)(sW2L0 + n * 136 + k0 + 8) = q1;
            q0 = make_uint4(PK(t2,0), PK(t2,2), PK(t2,4), PK(t2,6));
            q1 = make_uint4(PK(t2,8), PK(t2,10), PK(t2,12), PK(t2,14));
            *(uint4*)(sW2L1 + n * 136 + k0) = q0; *(uint4*)(sW2L1 + n * 136 + k0 + 8) = q1;
            q0 = make_uint4(PK(t3,0), PK(t3,2), PK(t3,4), PK(t3,6));
            q1 = make_uint4(PK(t3,8), PK(t3,10), PK(t3,12), PK(t3,14));
            *(uint4*)(sW2L2 + n * 136 + k0) = q0; *(uint4*)(sW2L2 + n * 136 + k0 + 8) = q1;
        }
        #undef PK
    }

    // w1 3-limb B-fragments -> registers (global loads, L2-hot after first blocks)
    bf16x8 bw1[3][2][4];
    #pragma unroll
    for (int n2 = 0; n2 < 2; ++n2)
        #pragma unroll
        for (int ks = 0; ks < 4; ++ks) {
            int n  = wv * 32 + n2 * 16 + col;
            int k0 = ks * 32 + quad * 8;
            float v[8];
            if (k0 < 112) {
                const float* s = w1g + n * 112 + k0;
                float4 a = *(const float4*)s;
                float4 c = *(const float4*)(s + 4);
                v[0] = a.x; v[1] = a.y; v[2] = a.z; v[3] = a.w;
                v[4] = c.x; v[5] = c.y; v[6] = c.z; v[7] = c.w;
            } else {
                #pragma unroll
                for (int j = 0; j < 8; ++j) v[j] = 0.0f;
            }
            split3x8(v, bw1[0][n2][ks], bw1[1][n2][ks], bw1[2][n2][ks]);
        }
    const float b1v0 = b1g[wv * 32 + col];
    const float b1v1 = b1g[wv * 32 + 16 + col];
    const float b2v0 = b2g[col];
    const float b2v1 = b2g[16 + col];

    __syncthreads();   // B1: staging complete

    // save x values needed for the residual (sPf stable until h-write)
    float xs[2][4];
    #pragma unroll
    for (int n2 = 0; n2 < 2; ++n2)
        #pragma unroll
        for (int r = 0; r < 4; ++r)
            xs[n2][r] = sPf[(wv * 16 + quad * 4 + r) * 132 + n2 * 16 + col];

    // ---------------- Stage 1: h = relu(perc @ w1^T + b1), split-N over waves ----
    const f32x4 fz = {0.f, 0.f, 0.f, 0.f};
    f32x4 acc1[4][2];
    #pragma unroll
    for (int mt = 0; mt < 4; ++mt) { acc1[mt][0] = fz; acc1[mt][1] = fz; }

    #pragma unroll
    for (int mt = 0; mt < 4; ++mt) {
        const float* ap = &sPf[(mt * 16 + col) * 132];
        #pragma unroll
        for (int ks = 0; ks < 4; ++ks) {
            int k0 = ks * 32 + quad * 8;
            float v[8];
            float4 lo = *(const float4*)(ap + k0);
            float4 hi = *(const float4*)(ap + k0 + 4);
            v[0] = lo.x; v[1] = lo.y; v[2] = lo.z; v[3] = lo.w;
            v[4] = hi.x; v[5] = hi.y; v[6] = hi.z; v[7] = hi.w;
            bf16x8 A1, A2, A3;
            split3x8(v, A1, A2, A3);
            #pragma unroll
            for (int n2 = 0; n2 < 2; ++n2) {
                f32x4 a = acc1[mt][n2];
                a = __builtin_amdgcn_mfma_f32_16x16x32_bf16(A1, bw1[0][n2][ks], a, 0, 0, 0);
                a = __builtin_amdgcn_mfma_f32_16x16x32_bf16(A1, bw1[1][n2][ks], a, 0, 0, 0);
                a = __builtin_amdgcn_mfma_f32_16x16x32_bf16(A2, bw1[0][n2][ks], a, 0, 0, 0);
                a = __builtin_amdgcn_mfma_f32_16x16x32_bf16(A1, bw1[2][n2][ks], a, 0, 0, 0);
                a = __builtin_amdgcn_mfma_f32_16x16x32_bf16(A2, bw1[1][n2][ks], a, 0, 0, 0);
                a = __builtin_amdgcn_mfma_f32_16x16x32_bf16(A3, bw1[0][n2][ks], a, 0, 0, 0);
                acc1[mt][n2] = a;
            }
        }
    }
    __syncthreads();   // B2.5: all perc reads done -> sPf reusable for h (fp32)

    // h write (fp32, exact relu(acc+b1))
    #pragma unroll
    for (int mt = 0; mt < 4; ++mt)
        #pragma unroll
        for (int n2 = 0; n2 < 2; ++n2) {
            float bb = n2 ? b1v1 : b1v0;
            #pragma unroll
            for (int r = 0; r < 4; ++r)
                sPf[(mt * 16 + quad * 4 + r) * 132 + wv * 32 + n2 * 16 + col] =
                    fmaxf(acc1[mt][n2][r] + bb, 0.0f);
        }
    __syncthreads();   // B3: h complete

    // ---------------- Stage 2: dx = h @ w2^T, waves split-M (16 pixels each) ----
    f32x4 acc2[2];
    acc2[0] = fz; acc2[1] = fz;
    {
        const float* hp = &sPf[(wv * 16 + col) * 132];
        #pragma unroll
        for (int ks = 0; ks < 4; ++ks) {
            int k0 = ks * 32 + quad * 8;
            float v[8];
            float4 lo = *(const float4*)(hp + k0);
            float4 hi = *(const float4*)(hp + k0 + 4);
            v[0] = lo.x; v[1] = lo.y; v[2] = lo.z; v[3] = lo.w;
            v[4] = hi.x; v[5] = hi.y; v[6] = hi.z; v[7] = hi.w;
            bf16x8 H1, H2, H3;
            split3x8(v, H1, H2, H3);
            #pragma unroll
            for (int n2 = 0; n2 < 2; ++n2) {
                int boff = (n2 * 16 + col) * 136 + k0;
                bf16x8 B1 = *(const bf16x8*)&sW2L0[boff];
                bf16x8 B2 = *(const bf16x8*)&sW2L1[boff];
                bf16x8 B3 = *(const bf16x8*)&sW2L2[boff];
                f32x4 a = acc2[n2];
                a = __builtin_amdgcn_mfma_f32_16x16x32_bf16(H1, B1, a, 0, 0, 0);
                a = __builtin_amdgcn_mfma_f32_16x16x32_bf16(H1, B2, a, 0, 0, 0);
                a = __builtin_amdgcn_mfma_f32_16x16x32_bf16(H2, B1, a, 0, 0, 0);
                a = __builtin_amdgcn_mfma_f32_16x16x32_bf16(H1, B3, a, 0, 0, 0);
                a = __builtin_amdgcn_mfma_f32_16x16x32_bf16(H2, B2, a, 0, 0, 0);
                a = __builtin_amdgcn_mfma_f32_16x16x32_bf16(H3, B1, a, 0, 0, 0);
                acc2[n2] = a;
            }
        }
    }
    __syncthreads();   // B4a: stage-2 LDS reads done -> sW2L region reusable (dxl)

    // new_state = x + dx + b2 -> dxl f32 [64][33]
    #pragma unroll
    for (int n2 = 0; n2 < 2; ++n2) {
        float bb = n2 ? b2v1 : b2v0;
        int c = n2 * 16 + col;
        #pragma unroll
        for (int r = 0; r < 4; ++r) {
            int p = wv * 16 + quad * 4 + r;
            dxl[p * 33 + c] = acc2[n2][r] + bb + xs[n2][r];
        }
    }
    __syncthreads();   // B4: new_state complete

    // ---------------- Epilogue: mask + LayerNorm + fp32 store (wave 0) ---------
    if (tid < 64) {
        int p = tid;
        float ns[32];
        #pragma unroll
        for (int c = 0; c < 32; ++c) ns[c] = dxl[p * 33 + c];
        // argmax over classes 0..9 (ties -> first). keep hidden iff argmax != 0
        float m = ns[1];
        #pragma unroll
        for (int c = 2; c < 10; ++c) m = fmaxf(m, ns[c]);
        float keep = (m > ns[0]) ? 1.0f : 0.0f;
        #pragma unroll
        for (int c = 10; c < 32; ++c) ns[c] *= keep;
        float s = 0.f;
        #pragma unroll
        for (int c = 0; c < 32; ++c) s += ns[c];
        float mu = s * 0.03125f;
        float var = 0.f;
        #pragma unroll
        for (int c = 0; c < 32; ++c) { float d = ns[c] - mu; var += d * d; }
        var *= 0.03125f;
        float rstd = 1.0f / sqrtf(var + 1e-5f);
        int base = b * 524288 + irow * 128 + jbase + p;
        #pragma unroll
        for (int c = 0; c < 32; ++c) {
            outg[base + c * 16384] = (ns[c] - mu) * rstd * gg[c] + bg[c];  // coalesced fp32
        }
    }
}

extern "C" void kernel_launch(void* const* d_in, const int* in_sizes, int n_in,
                              void* d_out, int out_size, void* d_ws, size_t ws_size,
                              hipStream_t stream) {
    const float* x  = (const float*)d_in[0];
    const float* w1 = (const float*)d_in[1];
    const float* b1 = (const float*)d_in[2];
    const float* w2 = (const float*)d_in[3];
    const float* b2 = (const float*)d_in[4];
    const float* g  = (const float*)d_in[5];
    const float* be = (const float*)d_in[6];
    float* out = (float*)d_out;
    // grid: 64 (B) * 128 (rows) * 2 (W/64) = 16384 blocks
    hipLaunchKernelGGL(cann_kernel, dim3(16384), dim3(256), 0, stream,
                       x, w1, b1, w2, b2, g, be, out);
}

// Round 5
// 583.414 us; speedup vs baseline: 1.0094x; 1.0094x over previous
//
#include <hip/hip_runtime.h>

typedef unsigned short U16;
typedef unsigned int U32;
typedef __bf16 bf16;
typedef bf16 bf16x8 __attribute__((ext_vector_type(8)));
typedef U16  u16x8  __attribute__((ext_vector_type(8)));
typedef float f32x4 __attribute__((ext_vector_type(4)));

// Exact 3-limb bf16 chop split: a == a1 + a2 + a3 (fp32 24-bit significand
// = 3 x 8-bit bf16 limbs; bf16 exponent range == fp32 so no subnormal loss).
__device__ __forceinline__ void split3(float a, U16& o1, U16& o2, U16& o3) {
    U32 ua = __float_as_uint(a);
    float a1 = __uint_as_float(ua & 0xFFFF0000u);
    float r1 = a - a1;
    U32 u2 = __float_as_uint(r1);
    float a2 = __uint_as_float(u2 & 0xFFFF0000u);
    float r2 = r1 - a2;                     // exact in bf16 (<=8 sig bits left)
    o1 = (U16)(ua >> 16);
    o2 = (U16)(u2 >> 16);
    o3 = (U16)(__float_as_uint(r2) >> 16);
}

__device__ __forceinline__ void split3x8(const float v[8], bf16x8& A1, bf16x8& A2, bf16x8& A3) {
    u16x8 e1, e2, e3;
    #pragma unroll
    for (int j = 0; j < 8; ++j) { U16 a, b, c; split3(v[j], a, b, c); e1[j] = a; e2[j] = b; e3[j] = c; }
    A1 = __builtin_bit_cast(bf16x8, e1);
    A2 = __builtin_bit_cast(bf16x8, e2);
    A3 = __builtin_bit_cast(bf16x8, e3);
}

// ---------------- prep: split w1/w2 into bf16 limb planes in d_ws ----------
// w1L: [3][128 n][128 k] bf16 (k 112..127 zero)  = 98304 B at ws+0
// w2L: [3][32 n][128 k]  bf16                    = 24576 B at ws+98304
__global__ __launch_bounds__(256)
void prep_kernel(const float* __restrict__ w1g, const float* __restrict__ w2g,
                 U16* __restrict__ w1L, U16* __restrict__ w2L)
{
    int tid = blockIdx.x * 256 + threadIdx.x;
    if (tid < 2048) {                       // 128 rows x 16 slots of 8 k
        int n = tid >> 4, k0 = (tid & 15) << 3;
        float v[8];
        #pragma unroll
        for (int j = 0; j < 8; ++j) { int k = k0 + j; v[j] = (k < 112) ? w1g[n * 112 + k] : 0.0f; }
        bf16x8 L1, L2, L3; split3x8(v, L1, L2, L3);
        *(bf16x8*)(w1L + 0 * 16384 + n * 128 + k0) = L1;
        *(bf16x8*)(w1L + 1 * 16384 + n * 128 + k0) = L2;
        *(bf16x8*)(w1L + 2 * 16384 + n * 128 + k0) = L3;
    }
    if (tid < 512) {                        // 32 rows x 16 slots
        int n = tid >> 4, k0 = (tid & 15) << 3;
        float v[8];
        #pragma unroll
        for (int j = 0; j < 8; ++j) v[j] = w2g[n * 128 + k0 + j];
        bf16x8 L1, L2, L3; split3x8(v, L1, L2, L3);
        *(bf16x8*)(w2L + 0 * 4096 + n * 128 + k0) = L1;
        *(bf16x8*)(w2L + 1 * 4096 + n * 128 + k0) = L2;
        *(bf16x8*)(w2L + 2 * 4096 + n * 128 + k0) = L3;
    }
}

// ---------------- main ----------------------------------------------------
// B=64, C=32, H=W=128, PERC=112(pad->128), NHID=128, NCLS=10. fp32 in/out.
// block = 256 threads = 4 waves = 64 pixels (one b, one row, half width).
// LDS: 3 bf16 limb planes [64][136] (perc, then h); dxl f32 [64][33] aliases.
__global__ __launch_bounds__(256, 3)
void cann_kernel(const float* __restrict__ xg,  const U16* __restrict__ w1L,
                 const U16* __restrict__ w2L,
                 const float* __restrict__ b1g, const float* __restrict__ b2g,
                 const float* __restrict__ gg,  const float* __restrict__ bg,
                 float* __restrict__ outg)
{
    __shared__ __align__(16) U16 sL[3 * 8704];        // 52224 B -> 3 blocks/CU

    const int tid  = threadIdx.x;
    const int bid  = blockIdx.x;
    const int jseg = bid & 1;
    const int irow = (bid >> 1) & 127;
    const int b    = bid >> 8;
    const int jbase = jseg << 6;
    const int lane = tid & 63;
    const int wv   = tid >> 6;
    const int quad = lane >> 4;
    const int col  = lane & 15;

    // ---------------- Phase A: stage perc as 3 bf16 limb planes (split ONCE) --
    {
        // (a) channels 0..31: one thread = one pixel x 8 channels
        int px = tid & 63;
        int cg = tid >> 6;
        const float* src = xg + (b * 32 + cg * 8) * 16384 + irow * 128 + jbase + px;
        float v[8];
        #pragma unroll
        for (int i = 0; i < 8; ++i) v[i] = src[i * 16384];   // coalesced across lanes
        bf16x8 L1, L2, L3; split3x8(v, L1, L2, L3);
        int o = px * 136 + cg * 8;
        *(bf16x8*)&sL[o] = L1;
        *(bf16x8*)&sL[8704 + o] = L2;
        *(bf16x8*)&sL[17408 + o] = L3;

        // (b) taps: one job = one (cls, pixel) -> 8 contiguous channels
        #pragma unroll
        for (int pass = 0; pass < 3; ++pass) {
            int j = tid + pass * 256;                 // 640 jobs
            if (j < 640) {
                int tpx = j & 63, cls = j >> 6;
                const float* cbase = xg + (b * 32 + cls) * 16384;
                float tv[8];
                #pragma unroll
                for (int t = 0; t < 8; ++t) {
                    int di = (int)((0x22211000u >> (4 * t)) & 0xFu) - 1;
                    int dj = (int)((0x21020210u >> (4 * t)) & 0xFu) - 1;
                    int row = irow + di;
                    int cc  = jbase + tpx + dj;
                    tv[t] = ((unsigned)row < 128u && (unsigned)cc < 128u)
                            ? cbase[row * 128 + cc] : 0.0f;
                }
                bf16x8 T1, T2, T3; split3x8(tv, T1, T2, T3);
                int to = tpx * 136 + 32 + cls * 8;
                *(bf16x8*)&sL[to] = T1;
                *(bf16x8*)&sL[8704 + to] = T2;
                *(bf16x8*)&sL[17408 + to] = T3;
            }
        }
        // (c) zero pad k=112..127 in all 3 planes
        if (tid < 128) {
            int zo = (tid >> 1) * 136 + 112 + (tid & 1) * 8;
            uint4 z = make_uint4(0u, 0u, 0u, 0u);
            *(uint4*)&sL[zo] = z;
            *(uint4*)&sL[8704 + zo] = z;
            *(uint4*)&sL[17408 + zo] = z;
        }
    }

    // w1 limb B-fragments from prep'd global (L2-resident after first blocks)
    bf16x8 bw1[3][2][4];
    #pragma unroll
    for (int n2 = 0; n2 < 2; ++n2)
        #pragma unroll
        for (int ks = 0; ks < 4; ++ks) {
            int n  = wv * 32 + n2 * 16 + col;
            int k0 = ks * 32 + quad * 8;
            #pragma unroll
            for (int L = 0; L < 3; ++L)
                bw1[L][n2][ks] = *(const bf16x8*)(w1L + L * 16384 + n * 128 + k0);
        }
    const float b1v0 = b1g[wv * 32 + col];
    const float b1v1 = b1g[wv * 32 + 16 + col];
    const float b2v0 = b2g[col];
    const float b2v1 = b2g[16 + col];

    // residual x for this wave's stage-2 tile (global re-load, L1/L2-hot)
    float xs[2][4];
    #pragma unroll
    for (int n2 = 0; n2 < 2; ++n2)
        #pragma unroll
        for (int r = 0; r < 4; ++r)
            xs[n2][r] = xg[(b * 32 + n2 * 16 + col) * 16384 + irow * 128 + jbase
                           + wv * 16 + quad * 4 + r];

    __syncthreads();   // B1: staging complete

    // ---------------- Stage 1: h = relu(perc @ w1^T + b1), split-N over waves --
    const f32x4 fz = {0.f, 0.f, 0.f, 0.f};
    f32x4 acc1[4][2];
    #pragma unroll
    for (int mt = 0; mt < 4; ++mt) { acc1[mt][0] = fz; acc1[mt][1] = fz; }

    #pragma unroll
    for (int mt = 0; mt < 4; ++mt) {
        #pragma unroll
        for (int ks = 0; ks < 4; ++ks) {
            int ao = (mt * 16 + col) * 136 + ks * 32 + quad * 8;
            bf16x8 A1 = *(const bf16x8*)&sL[ao];
            bf16x8 A2 = *(const bf16x8*)&sL[8704 + ao];
            bf16x8 A3 = *(const bf16x8*)&sL[17408 + ao];
            #pragma unroll
            for (int n2 = 0; n2 < 2; ++n2) {
                f32x4 a = acc1[mt][n2];
                a = __builtin_amdgcn_mfma_f32_16x16x32_bf16(A1, bw1[0][n2][ks], a, 0, 0, 0);
                a = __builtin_amdgcn_mfma_f32_16x16x32_bf16(A1, bw1[1][n2][ks], a, 0, 0, 0);
                a = __builtin_amdgcn_mfma_f32_16x16x32_bf16(A2, bw1[0][n2][ks], a, 0, 0, 0);
                a = __builtin_amdgcn_mfma_f32_16x16x32_bf16(A1, bw1[2][n2][ks], a, 0, 0, 0);
                a = __builtin_amdgcn_mfma_f32_16x16x32_bf16(A2, bw1[1][n2][ks], a, 0, 0, 0);
                a = __builtin_amdgcn_mfma_f32_16x16x32_bf16(A3, bw1[0][n2][ks], a, 0, 0, 0);
                acc1[mt][n2] = a;
            }
        }
    }
    __syncthreads();   // B2: all perc reads done -> planes reusable for h

    // h -> 3 limb planes (exact split of relu(acc+b1))
    #pragma unroll
    for (int mt = 0; mt < 4; ++mt)
        #pragma unroll
        for (int n2 = 0; n2 < 2; ++n2) {
            float bb = n2 ? b1v1 : b1v0;
            #pragma unroll
            for (int r = 0; r < 4; ++r) {
                float v = fmaxf(acc1[mt][n2][r] + bb, 0.0f);
                U16 u1, u2, u3; split3(v, u1, u2, u3);
                int ho = (mt * 16 + quad * 4 + r) * 136 + wv * 32 + n2 * 16 + col;
                sL[ho] = u1; sL[8704 + ho] = u2; sL[17408 + ho] = u3;
            }
        }
    __syncthreads();   // B3: h complete

    // ---------------- Stage 2: dx = h @ w2^T, waves split-M (16 pixels each) ---
    f32x4 acc2[2];
    acc2[0] = fz; acc2[1] = fz;
    #pragma unroll
    for (int ks = 0; ks < 4; ++ks) {
        int k0 = ks * 32 + quad * 8;
        int ho = (wv * 16 + col) * 136 + k0;
        bf16x8 H1 = *(const bf16x8*)&sL[ho];
        bf16x8 H2 = *(const bf16x8*)&sL[8704 + ho];
        bf16x8 H3 = *(const bf16x8*)&sL[17408 + ho];
        #pragma unroll
        for (int n2 = 0; n2 < 2; ++n2) {
            int bo = (n2 * 16 + col) * 128 + k0;
            bf16x8 B1 = *(const bf16x8*)(w2L + 0 * 4096 + bo);   // L2-hot, per-ks
            bf16x8 B2 = *(const bf16x8*)(w2L + 1 * 4096 + bo);   //  -> low VGPR
            bf16x8 B3 = *(const bf16x8*)(w2L + 2 * 4096 + bo);
            f32x4 a = acc2[n2];
            a = __builtin_amdgcn_mfma_f32_16x16x32_bf16(H1, B1, a, 0, 0, 0);
            a = __builtin_amdgcn_mfma_f32_16x16x32_bf16(H1, B2, a, 0, 0, 0);
            a = __builtin_amdgcn_mfma_f32_16x16x32_bf16(H2, B1, a, 0, 0, 0);
            a = __builtin_amdgcn_mfma_f32_16x16x32_bf16(H1, B3, a, 0, 0, 0);
            a = __builtin_amdgcn_mfma_f32_16x16x32_bf16(H2, B2, a, 0, 0, 0);
            a = __builtin_amdgcn_mfma_f32_16x16x32_bf16(H3, B1, a, 0, 0, 0);
            acc2[n2] = a;
        }
    }
    __syncthreads();   // B4a: stage-2 LDS reads done -> plane mem reusable (dxl)

    // new_state = x + dx + b2 -> dxl f32 [64][33]
    float* dxl = (float*)sL;
    #pragma unroll
    for (int n2 = 0; n2 < 2; ++n2) {
        float bb = n2 ? b2v1 : b2v0;
        int c = n2 * 16 + col;
        #pragma unroll
        for (int r = 0; r < 4; ++r) {
            int p = wv * 16 + quad * 4 + r;
            dxl[p * 33 + c] = acc2[n2][r] + bb + xs[n2][r];
        }
    }
    __syncthreads();   // B4: new_state complete

    // ---------------- Epilogue: mask + LayerNorm + fp32 store (wave 0) ---------
    if (tid < 64) {
        int p = tid;
        float ns[32];
        #pragma unroll
        for (int c = 0; c < 32; ++c) ns[c] = dxl[p * 33 + c];
        // argmax over classes 0..9 (ties -> first). keep hidden iff argmax != 0
        float m = ns[1];
        #pragma unroll
        for (int c = 2; c < 10; ++c) m = fmaxf(m, ns[c]);
        float keep = (m > ns[0]) ? 1.0f : 0.0f;
        #pragma unroll
        for (int c = 10; c < 32; ++c) ns[c] *= keep;
        float s = 0.f;
        #pragma unroll
        for (int c = 0; c < 32; ++c) s += ns[c];
        float mu = s * 0.03125f;
        float var = 0.f;
        #pragma unroll
        for (int c = 0; c < 32; ++c) { float d = ns[c] - mu; var += d * d; }
        var *= 0.03125f;
        float rstd = 1.0f / sqrtf(var + 1e-5f);
        int base = b * 524288 + irow * 128 + jbase + p;
        #pragma unroll
        for (int c = 0; c < 32; ++c)
            outg[base + c * 16384] = (ns[c] - mu) * rstd * gg[c] + bg[c];  // coalesced
    }
}

extern "C" void kernel_launch(void* const* d_in, const int* in_sizes, int n_in,
                              void* d_out, int out_size, void* d_ws, size_t ws_size,
                              hipStream_t stream) {
    const float* x  = (const float*)d_in[0];
    const float* w1 = (const float*)d_in[1];
    const float* b1 = (const float*)d_in[2];
    const float* w2 = (const float*)d_in[3];
    const float* b2 = (const float*)d_in[4];
    const float* g  = (const float*)d_in[5];
    const float* be = (const float*)d_in[6];
    float* out = (float*)d_out;

    U16* w1L = (U16*)d_ws;                       // 98304 B
    U16* w2L = (U16*)((char*)d_ws + 98304);      // 24576 B (total 122880 <= ws)

    hipLaunchKernelGGL(prep_kernel, dim3(8), dim3(256), 0, stream, w1, w2, w1L, w2L);
    // grid: 64 (B) * 128 (rows) * 2 (W/64) = 16384 blocks
    hipLaunchKernelGGL(cann_kernel, dim3(16384), dim3(256), 0, stream,
                       x, w1L, w2L, b1, b2, g, be, out);
}